// Round 1
// baseline (549.436 us; speedup 1.0000x reference)
//
#include <hip/hip_runtime.h>
#include <math.h>

// B=2, S=2048, D=1024, H=16, DK=64, NUM_BUCKETS=32, MAX_DIST=128, SM_SCALE=0.25

typedef _Float16 f16;
typedef _Float16 f16x4 __attribute__((ext_vector_type(4)));
typedef _Float16 f16x8 __attribute__((ext_vector_type(8)));
typedef float f32x4 __attribute__((ext_vector_type(4)));

#define MFMA16(a, b, c) __builtin_amdgcn_mfma_f32_16x16x32_f16((a), (b), (c), 0, 0, 0)

// ---------------------------------------------------------------- prep kernels

// X (fp32, 4096x1024) -> f16
__global__ __launch_bounds__(256) void cast_x_kernel(const float4* __restrict__ x,
                                                     f16x4* __restrict__ xh) {
  int i = blockIdx.x * 256 + threadIdx.x;  // grid sized exactly: 1048576 threads
  float4 v = x[i];
  f16x4 o;
  o[0] = (f16)v.x; o[1] = (f16)v.y; o[2] = (f16)v.z; o[3] = (f16)v.w;
  xh[i] = o;
}

// W[k][n] (1024x1024 fp32) -> Wt[z*1024 + n][k] f16, z in {Wq,Wk,Wv,Wo}
__global__ void transpose_w_kernel(const float* __restrict__ w0, const float* __restrict__ w1,
                                   const float* __restrict__ w2, const float* __restrict__ w3,
                                   f16* __restrict__ wt) {
  int z = blockIdx.z;
  const float* w = (z == 0) ? w0 : (z == 1) ? w1 : (z == 2) ? w2 : w3;
  __shared__ float tile[32][33];
  int tx = threadIdx.x, ty = threadIdx.y;
  int kt = blockIdx.x * 32, nt = blockIdx.y * 32;
#pragma unroll
  for (int i = 0; i < 4; ++i)
    tile[ty + i * 8][tx] = w[(size_t)(kt + ty + i * 8) * 1024 + nt + tx];
  __syncthreads();
#pragma unroll
  for (int i = 0; i < 4; ++i)
    wt[((size_t)z * 1024 + nt + ty + i * 8) * 1024 + kt + tx] = (f16)tile[tx][ty + i * 8];
}

// T5 relative-position bias table: bias_rel[h][rp + 2047], rp in [-2047, 2047]
__global__ __launch_bounds__(256) void bias_kernel(const float* __restrict__ rel_bias,
                                                   float* __restrict__ bias_rel) {
  int idx = blockIdx.x * 256 + threadIdx.x;
  if (idx >= 16 * 4095) return;
  int h = idx / 4095;
  int r = idx - h * 4095;
  int rp = r - 2047;
  int bucket = (rp > 0) ? 16 : 0;
  int rpa = (rp < 0) ? -rp : rp;
  if (rpa < 8) {
    bucket += rpa;
  } else {
    int large = 8 + (int)(logf((float)rpa / 8.0f) / logf(16.0f) * 8.0f);
    bucket += (large < 15) ? large : 15;
  }
  bias_rel[idx] = rel_bias[bucket * 16 + h];
}

// ---------------------------------------------------------------- GEMM core
// C tile: 16 rows (this wave) x 64 cols. A[m][k] f16 row-major, Bt[n][k] f16 row-major.
// K = 1024. A-frag: lane reads A[mrow + (lane&15)][kk*32 + 8*(lane>>4) .. +7].

__device__ __forceinline__ void gemm_core64(const f16* __restrict__ A, const f16* __restrict__ Bt,
                                            int mrow, int ntile, int lane, f32x4* acc) {
  const int cL = lane & 15, g = lane >> 4;
  const f16* ap = A + (mrow + cL) * 1024 + 8 * g;
  const f16* bp = Bt + (ntile + cL) * 1024 + 8 * g;
#pragma unroll 4
  for (int kk = 0; kk < 32; ++kk) {
    f16x8 a = *(const f16x8*)(ap + kk * 32);
#pragma unroll
    for (int n = 0; n < 4; ++n) {
      f16x8 b = *(const f16x8*)(bp + n * 16384 + kk * 32);
      acc[n] = MFMA16(a, b, acc[n]);
    }
  }
}

// QKV projection: Xh(4096x1024) @ Wt[0..3071][k] -> Q,K [b][h][s][dk], V^T [b][h][dk][s]
__global__ __launch_bounds__(256) void gemm_qkv_kernel(const f16* __restrict__ Xh,
                                                       const f16* __restrict__ Wt,
                                                       f16* __restrict__ Qh,
                                                       f16* __restrict__ Kh,
                                                       f16* __restrict__ Vt) {
  int lane = threadIdx.x & 63, wave = threadIdx.x >> 6;
  int mrow = blockIdx.y * 64 + wave * 16;
  int ntile = blockIdx.x * 64;
  f32x4 acc[4] = {};
  gemm_core64(Xh, Wt, mrow, ntile, lane, acc);
  int cL = lane & 15, g = lane >> 4;
  int which = ntile >> 10;  // uniform per block
#pragma unroll
  for (int n = 0; n < 4; ++n) {
#pragma unroll
    for (int r = 0; r < 4; ++r) {
      int t = mrow + g * 4 + r;
      int b = t >> 11, s = t & 2047;
      int col = (ntile + n * 16 + cL) & 1023;
      int hh = col >> 6, dk = col & 63;
      f16 val = (f16)acc[n][r];
      if (which == 0)
        Qh[(((size_t)b * 16 + hh) * 2048 + s) * 64 + dk] = val;
      else if (which == 1)
        Kh[(((size_t)b * 16 + hh) * 2048 + s) * 64 + dk] = val;
      else
        Vt[(((size_t)b * 16 + hh) * 64 + dk) * 2048 + s] = val;
    }
  }
}

// Output projection: Oh(4096x1024) @ Wo -> d_out fp32
__global__ __launch_bounds__(256) void gemm_out_kernel(const f16* __restrict__ Oh,
                                                       const f16* __restrict__ WoT,
                                                       float* __restrict__ out) {
  int lane = threadIdx.x & 63, wave = threadIdx.x >> 6;
  int mrow = blockIdx.y * 64 + wave * 16;
  int ntile = blockIdx.x * 64;
  f32x4 acc[4] = {};
  gemm_core64(Oh, WoT, mrow, ntile, lane, acc);
  int cL = lane & 15, g = lane >> 4;
#pragma unroll
  for (int n = 0; n < 4; ++n) {
#pragma unroll
    for (int r = 0; r < 4; ++r) {
      int t = mrow + g * 4 + r;
      out[(size_t)t * 1024 + ntile + n * 16 + cL] = acc[n][r];
    }
  }
}

// ---------------------------------------------------------------- attention
// Grid (S/64, B*H). 4 waves/block, each wave owns 16 q-rows, iterates 32 K-tiles of 64.
__global__ __launch_bounds__(256) void attn_kernel(const f16* __restrict__ Qh,
                                                   const f16* __restrict__ Kh,
                                                   const f16* __restrict__ Vt,
                                                   const float* __restrict__ bias_rel,
                                                   f16* __restrict__ Oh) {
  __shared__ f16x8 smem8[512];  // 8 KB: 2 KB per wave P round-trip buffer
  int bh = blockIdx.y;
  int h = bh & 15, b = bh >> 4;
  int qt = blockIdx.x * 64;
  int lane = threadIdx.x & 63, wave = threadIdx.x >> 6;
  int cL = lane & 15, g = lane >> 4;

  const size_t bhS = (size_t)bh * 2048;
  // Q A-fragments (held for whole kernel)
  const f16* qp = Qh + (bhS + qt + wave * 16 + cL) * 64 + 8 * g;
  f16x8 qa0 = *(const f16x8*)qp;
  f16x8 qa1 = *(const f16x8*)(qp + 32);

  const float* brh = bias_rel + h * 4095 + 2047;
  const int qrow0 = qt + wave * 16 + g * 4;  // C-layout row base for this lane

  f32x4 o[4] = {};
  float m[4] = {-INFINITY, -INFINITY, -INFINITY, -INFINITY};
  float lsum[4] = {0.f, 0.f, 0.f, 0.f};
  char* pbase = (char*)smem8 + wave * 2048;
  const int sw = (cL & 7) << 4;

  for (int kt = 0; kt < 32; ++kt) {
    const int key0 = kt * 64;
    // ---- S = Q K^T  (4 col-tiles x 2 k-steps)
    f32x4 sa[4] = {};
    const f16* kp = Kh + (bhS + key0 + cL) * 64 + 8 * g;
#pragma unroll
    for (int n = 0; n < 4; ++n) {
      f16x8 b0 = *(const f16x8*)(kp + n * 1024);        // n*16 keys * 64
      f16x8 b1 = *(const f16x8*)(kp + n * 1024 + 32);
      sa[n] = MFMA16(qa0, b0, sa[n]);
      sa[n] = MFMA16(qa1, b1, sa[n]);
    }
    // ---- scale + bias
    float sx[4][4];
#pragma unroll
    for (int n = 0; n < 4; ++n) {
      int key = key0 + n * 16 + cL;
#pragma unroll
      for (int r = 0; r < 4; ++r)
        sx[n][r] = fmaf(sa[n][r], 0.25f, brh[key - (qrow0 + r)]);
    }
    // ---- online softmax (row = qrow0 + r, spread over 16-lane group)
#pragma unroll
    for (int r = 0; r < 4; ++r) {
      float mx = fmaxf(fmaxf(sx[0][r], sx[1][r]), fmaxf(sx[2][r], sx[3][r]));
      mx = fmaxf(mx, __shfl_xor(mx, 1));
      mx = fmaxf(mx, __shfl_xor(mx, 2));
      mx = fmaxf(mx, __shfl_xor(mx, 4));
      mx = fmaxf(mx, __shfl_xor(mx, 8));
      float mn = fmaxf(m[r], mx);
      float corr = __expf(m[r] - mn);
      float ps = 0.f;
#pragma unroll
      for (int n = 0; n < 4; ++n) {
        float p = __expf(sx[n][r] - mn);
        sx[n][r] = p;
        ps += p;
      }
      ps += __shfl_xor(ps, 1);
      ps += __shfl_xor(ps, 2);
      ps += __shfl_xor(ps, 4);
      ps += __shfl_xor(ps, 8);
      lsum[r] = lsum[r] * corr + ps;
      m[r] = mn;
#pragma unroll
      for (int n = 0; n < 4; ++n) o[n][r] *= corr;
    }
    // ---- P: C-layout regs -> XOR-swizzled LDS -> A-layout fragments
#pragma unroll
    for (int n = 0; n < 4; ++n) {
#pragma unroll
      for (int r = 0; r < 4; ++r) {
        int row = g * 4 + r;
        int byte = row * 128 + ((((n * 16 + cL) * 2)) ^ ((row & 7) << 4));
        *(f16*)(pbase + byte) = (f16)sx[n][r];
      }
    }
    asm volatile("s_waitcnt lgkmcnt(0)" ::: "memory");
    int rb = cL * 128;
    f16x8 pa0 = *(const f16x8*)(pbase + rb + ((g * 16) ^ sw));
    f16x8 pa1 = *(const f16x8*)(pbase + rb + ((64 + g * 16) ^ sw));
    // ---- O += P V   (V^T[dk][s] is the B-operand, contiguous along keys)
    const f16* vp = Vt + ((size_t)bh * 64 + cL) * 2048 + key0 + 8 * g;
#pragma unroll
    for (int n = 0; n < 4; ++n) {
      f16x8 v0 = *(const f16x8*)(vp + n * 32768);       // n*16 dk rows * 2048
      f16x8 v1 = *(const f16x8*)(vp + n * 32768 + 32);
      o[n] = MFMA16(pa0, v0, o[n]);
      o[n] = MFMA16(pa1, v1, o[n]);
    }
  }
  // ---- epilogue: O/l -> Oh[b][s][h*64+dk] f16
#pragma unroll
  for (int r = 0; r < 4; ++r) {
    float inv = 1.0f / lsum[r];
    int q = qrow0 + r;
    size_t rowoff = ((size_t)b * 2048 + q) * 1024 + h * 64;
#pragma unroll
    for (int n = 0; n < 4; ++n)
      Oh[rowoff + n * 16 + cL] = (f16)(o[n][r] * inv);
  }
}

// ---------------------------------------------------------------- launch

extern "C" void kernel_launch(void* const* d_in, const int* in_sizes, int n_in,
                              void* d_out, int out_size, void* d_ws, size_t ws_size,
                              hipStream_t stream) {
  const float* X = (const float*)d_in[0];
  const float* Wq = (const float*)d_in[1];
  const float* Wk = (const float*)d_in[2];
  const float* Wv = (const float*)d_in[3];
  const float* Wo = (const float*)d_in[4];
  const float* relb = (const float*)d_in[5];

  const size_t MB8 = (size_t)8 << 20;
  if (ws_size < 6 * MB8 + (size_t)(16 * 4095) * 4) return;  // need ~48.3 MB

  char* ws = (char*)d_ws;
  f16* Xh = (f16*)(ws + 0 * MB8);
  f16* Wt = (f16*)(ws + 1 * MB8);  // rows 0-1023 Wq^T, 1024-2047 Wk^T, 2048-3071 Wv^T, 3072-4095 Wo^T
  f16* Qh = (f16*)(ws + 2 * MB8);
  f16* Kh = (f16*)(ws + 3 * MB8);
  f16* Vt = (f16*)(ws + 4 * MB8);
  f16* Oh = (f16*)(ws + 5 * MB8);
  float* brel = (float*)(ws + 6 * MB8);

  cast_x_kernel<<<dim3(4096), dim3(256), 0, stream>>>((const float4*)X, (f16x4*)Xh);
  transpose_w_kernel<<<dim3(32, 32, 4), dim3(32, 8), 0, stream>>>(Wq, Wk, Wv, Wo, Wt);
  bias_kernel<<<dim3(256), dim3(256), 0, stream>>>(relb, brel);
  gemm_qkv_kernel<<<dim3(48, 64), dim3(256), 0, stream>>>(Xh, Wt, Qh, Kh, Vt);
  attn_kernel<<<dim3(32, 32), dim3(256), 0, stream>>>(Qh, Kh, Vt, brel, Oh);
  gemm_out_kernel<<<dim3(16, 64), dim3(256), 0, stream>>>(Oh, Wt + (size_t)3072 * 1024,
                                                          (float*)d_out);
}

// Round 2
// 196.439 us; speedup vs baseline: 2.7970x; 2.7970x over previous
//
#include <hip/hip_runtime.h>
#include <math.h>

// B=2, S=2048, D=1024, H=16, DK=64, NUM_BUCKETS=32, MAX_DIST=128, SM_SCALE=0.25

typedef _Float16 f16;
typedef _Float16 f16x4 __attribute__((ext_vector_type(4)));
typedef _Float16 f16x8 __attribute__((ext_vector_type(8)));
typedef float f32x4 __attribute__((ext_vector_type(4)));

#define MFMA16(a, b, c) __builtin_amdgcn_mfma_f32_16x16x32_f16((a), (b), (c), 0, 0, 0)

// async global->LDS, 16B per lane; lds base must be wave-uniform (HW adds lane*16)
__device__ __forceinline__ void gload16(const f16* g, f16* l) {
  __builtin_amdgcn_global_load_lds(
      (const __attribute__((address_space(1))) void*)g,
      (__attribute__((address_space(3))) void*)l, 16, 0, 0);
}

// ---------------------------------------------------------------- prep kernels

__global__ __launch_bounds__(256) void cast_x_kernel(const float4* __restrict__ x,
                                                     f16x4* __restrict__ xh) {
  int i = blockIdx.x * 256 + threadIdx.x;
  float4 v = x[i];
  f16x4 o;
  o[0] = (f16)v.x; o[1] = (f16)v.y; o[2] = (f16)v.z; o[3] = (f16)v.w;
  xh[i] = o;
}

// W[k][n] (1024x1024 fp32) -> Wt[z*1024 + n][k] f16
__global__ void transpose_w_kernel(const float* __restrict__ w0, const float* __restrict__ w1,
                                   const float* __restrict__ w2, const float* __restrict__ w3,
                                   f16* __restrict__ wt) {
  int z = blockIdx.z;
  const float* w = (z == 0) ? w0 : (z == 1) ? w1 : (z == 2) ? w2 : w3;
  __shared__ float tile[32][33];
  int tx = threadIdx.x, ty = threadIdx.y;
  int kt = blockIdx.x * 32, nt = blockIdx.y * 32;
#pragma unroll
  for (int i = 0; i < 4; ++i)
    tile[ty + i * 8][tx] = w[(size_t)(kt + ty + i * 8) * 1024 + nt + tx];
  __syncthreads();
#pragma unroll
  for (int i = 0; i < 4; ++i)
    wt[((size_t)z * 1024 + nt + ty + i * 8) * 1024 + kt + tx] = (f16)tile[tx][ty + i * 8];
}

// T5 bias table: bias_rel[h][rp + 2047]
__global__ __launch_bounds__(256) void bias_kernel(const float* __restrict__ rel_bias,
                                                   float* __restrict__ bias_rel) {
  int idx = blockIdx.x * 256 + threadIdx.x;
  if (idx >= 16 * 4095) return;
  int h = idx / 4095;
  int r = idx - h * 4095;
  int rp = r - 2047;
  int bucket = (rp > 0) ? 16 : 0;
  int rpa = (rp < 0) ? -rp : rp;
  if (rpa < 8) {
    bucket += rpa;
  } else {
    int large = 8 + (int)(logf((float)rpa / 8.0f) / logf(16.0f) * 8.0f);
    bucket += (large < 15) ? large : 15;
  }
  bias_rel[idx] = rel_bias[bucket * 16 + h];
}

// ---------------------------------------------------------------- GEMM 128x128, BK=32
// A[m][k], Bt[n][k] row-major f16, K=1024. LDS tile [128][32] f16 (64B rows, 4 chunks),
// chunk swizzle c ^= (row&3) applied on BOTH the pre-swizzled global source and the read.
// Double-buffered; one __syncthreads per K-step (T3-minimum 2-phase).

__device__ __forceinline__ void gemm128_core(const f16* __restrict__ A, const f16* __restrict__ Bt,
                                             int mrow, int ncol0, f16* sm /*[2][8192]*/,
                                             f32x4 acc[4][4]) {
  const int t = threadIdx.x;
  const int lane = t & 63, w = t >> 6;
  const int cL = lane & 15, g = lane >> 4;
  const int wr = w >> 1, wc = w & 1;

  // staging descriptors: chunk idx c0/c1 for this thread's 2 A-chunks and 2 B-chunks
  const int c0 = w * 128 + lane;  // (w*2+0)*64 + lane
  const int c1 = c0 + 64;
  const int rA0 = c0 >> 2, kA0 = ((c0 & 3) ^ (rA0 & 3)) << 3;
  const int rA1 = c1 >> 2, kA1 = ((c1 & 3) ^ (rA1 & 3)) << 3;
  const f16* gA0 = A + (size_t)(mrow + rA0) * 1024 + kA0;
  const f16* gA1 = A + (size_t)(mrow + rA1) * 1024 + kA1;
  const f16* gB0 = Bt + (size_t)(ncol0 + rA0) * 1024 + kA0;
  const f16* gB1 = Bt + (size_t)(ncol0 + rA1) * 1024 + kA1;
  const int lds0 = (w * 2) * 512, lds1 = (w * 2 + 1) * 512;

#define GSTAGE(buf, k0)                            \
  do {                                             \
    f16* s_ = sm + (buf) * 8192;                   \
    gload16(gA0 + (k0), s_ + lds0);                \
    gload16(gA1 + (k0), s_ + lds1);                \
    gload16(gB0 + (k0), s_ + 4096 + lds0);         \
    gload16(gB1 + (k0), s_ + 4096 + lds1);         \
  } while (0)

  GSTAGE(0, 0);
  __syncthreads();
#pragma unroll 2
  for (int ks = 0; ks < 32; ++ks) {
    const int cur = ks & 1;
    if (ks < 31) GSTAGE(cur ^ 1, (ks + 1) * 32);
    const f16* bA = sm + cur * 8192;
    const f16* bB = bA + 4096;
    f16x8 af[4], bf[4];
#pragma unroll
    for (int m = 0; m < 4; ++m) {
      int r = wr * 64 + m * 16 + cL;
      af[m] = *(const f16x8*)&bA[r * 32 + ((g ^ (r & 3)) << 3)];
    }
#pragma unroll
    for (int n = 0; n < 4; ++n) {
      int r = wc * 64 + n * 16 + cL;
      bf[n] = *(const f16x8*)&bB[r * 32 + ((g ^ (r & 3)) << 3)];
    }
#pragma unroll
    for (int m = 0; m < 4; ++m)
#pragma unroll
      for (int n = 0; n < 4; ++n) acc[m][n] = MFMA16(af[m], bf[n], acc[m][n]);
    __syncthreads();
  }
#undef GSTAGE
}

// QKV projection -> Q,K [b][h][s][dk], V^T [b][h][dk][s]
__global__ __launch_bounds__(256) void gemm_qkv_kernel(const f16* __restrict__ Xh,
                                                       const f16* __restrict__ Wt,
                                                       f16* __restrict__ Qh,
                                                       f16* __restrict__ Kh,
                                                       f16* __restrict__ Vt) {
  __shared__ __align__(16) f16 sm[2][8192];
  int mrow = blockIdx.y * 128, ncol0 = blockIdx.x * 128;
  f32x4 acc[4][4] = {};
  gemm128_core(Xh, Wt, mrow, ncol0, &sm[0][0], acc);
  int lane = threadIdx.x & 63, w = threadIdx.x >> 6;
  int cL = lane & 15, g = lane >> 4;
  int wr = w >> 1, wc = w & 1;
  int which = (ncol0 + wc * 64) >> 10;  // uniform per wave
#pragma unroll
  for (int m = 0; m < 4; ++m) {
#pragma unroll
    for (int n = 0; n < 4; ++n) {
#pragma unroll
      for (int r = 0; r < 4; ++r) {
        int tt = mrow + wr * 64 + m * 16 + g * 4 + r;
        int b = tt >> 11, s = tt & 2047;
        int col = (ncol0 + wc * 64 + n * 16 + cL) & 1023;
        int hh = col >> 6, dk = col & 63;
        f16 val = (f16)acc[m][n][r];
        if (which == 0)
          Qh[(((size_t)b * 16 + hh) * 2048 + s) * 64 + dk] = val;
        else if (which == 1)
          Kh[(((size_t)b * 16 + hh) * 2048 + s) * 64 + dk] = val;
        else
          Vt[(((size_t)b * 16 + hh) * 64 + dk) * 2048 + s] = val;
      }
    }
  }
}

// Output projection -> fp32 d_out
__global__ __launch_bounds__(256) void gemm_out_kernel(const f16* __restrict__ Oh,
                                                       const f16* __restrict__ WoT,
                                                       float* __restrict__ out) {
  __shared__ __align__(16) f16 sm[2][8192];
  int mrow = blockIdx.y * 128, ncol0 = blockIdx.x * 128;
  f32x4 acc[4][4] = {};
  gemm128_core(Oh, WoT, mrow, ncol0, &sm[0][0], acc);
  int lane = threadIdx.x & 63, w = threadIdx.x >> 6;
  int cL = lane & 15, g = lane >> 4;
  int wr = w >> 1, wc = w & 1;
#pragma unroll
  for (int m = 0; m < 4; ++m)
#pragma unroll
    for (int n = 0; n < 4; ++n)
#pragma unroll
      for (int r = 0; r < 4; ++r) {
        int tt = mrow + wr * 64 + m * 16 + g * 4 + r;
        out[(size_t)tt * 1024 + ncol0 + wc * 64 + n * 16 + cL] = acc[m][n][r];
      }
}

// ---------------------------------------------------------------- attention
// Grid (S/64, B*H), 4 waves/block each owning 16 q-rows. K/V tiles (64x64 f16 each)
// double-buffered in LDS via global_load_lds, shared by all 4 waves; chunk swizzle
// c ^= (row&7) on 128B rows. One __syncthreads per K-tile.
__global__ __launch_bounds__(256) void attn_kernel(const f16* __restrict__ Qh,
                                                   const f16* __restrict__ Kh,
                                                   const f16* __restrict__ Vt,
                                                   const float* __restrict__ bias_rel,
                                                   f16* __restrict__ Oh) {
  __shared__ __align__(16) f16 sKV[2][8192];  // [buf][ K 4096 | V 4096 ]
  __shared__ __align__(16) char sP[4][2048];  // per-wave P roundtrip
  int bh = blockIdx.y;
  int h = bh & 15, b = bh >> 4;
  int qt = blockIdx.x * 64;
  int lane = threadIdx.x & 63, wave = threadIdx.x >> 6;
  int cL = lane & 15, g = lane >> 4;
  const size_t bhS = (size_t)bh * 2048;

  // Q A-fragments
  const f16* qp = Qh + (bhS + qt + wave * 16 + cL) * 64 + 8 * g;
  f16x8 qa0 = *(const f16x8*)qp;
  f16x8 qa1 = *(const f16x8*)(qp + 32);

  // staging descriptors (chunk = 16B = 8 f16; 8 chunks per 64-f16 row)
  const int c0 = wave * 128 + lane;
  const int c1 = c0 + 64;
  const int r0 = c0 >> 3, cc0 = ((c0 & 7) ^ (r0 & 7)) << 3;
  const int r1 = c1 >> 3, cc1 = ((c1 & 7) ^ (r1 & 7)) << 3;
  const f16* gK0 = Kh + (bhS + r0) * 64 + cc0;
  const f16* gK1 = Kh + (bhS + r1) * 64 + cc1;
  const f16* gV0 = Vt + ((size_t)bh * 64 + r0) * 2048 + cc0;
  const f16* gV1 = Vt + ((size_t)bh * 64 + r1) * 2048 + cc1;
  const int lds0 = (wave * 2) * 512, lds1 = (wave * 2 + 1) * 512;

#define ASTAGE(buf, key0)                          \
  do {                                             \
    f16* s_ = &sKV[buf][0];                        \
    gload16(gK0 + (size_t)(key0) * 64, s_ + lds0); \
    gload16(gK1 + (size_t)(key0) * 64, s_ + lds1); \
    gload16(gV0 + (key0), s_ + 4096 + lds0);       \
    gload16(gV1 + (key0), s_ + 4096 + lds1);       \
  } while (0)

  const float* brh = bias_rel + h * 4095 + 2047;
  const int qrow0 = qt + wave * 16 + g * 4;

  f32x4 o[4] = {};
  float m[4] = {-INFINITY, -INFINITY, -INFINITY, -INFINITY};
  float lsum[4] = {0.f, 0.f, 0.f, 0.f};
  char* pbase = sP[wave];
  const int sw = (cL & 7) << 4;

  ASTAGE(0, 0);
  __syncthreads();
  for (int kt = 0; kt < 32; ++kt) {
    const int cur = kt & 1;
    if (kt < 31) ASTAGE(cur ^ 1, (kt + 1) * 64);
    const int key0 = kt * 64;
    const f16* kb = &sKV[cur][0];
    const f16* vb = kb + 4096;
    // ---- S = Q K^T from LDS
    f32x4 sa[4] = {};
#pragma unroll
    for (int n = 0; n < 4; ++n) {
      int key = n * 16 + cL;
      f16x8 b0 = *(const f16x8*)&kb[key * 64 + ((g ^ (key & 7)) << 3)];
      f16x8 b1 = *(const f16x8*)&kb[key * 64 + (((g + 4) ^ (key & 7)) << 3)];
      sa[n] = MFMA16(qa0, b0, sa[n]);
      sa[n] = MFMA16(qa1, b1, sa[n]);
    }
    // ---- scale + bias
    float sx[4][4];
#pragma unroll
    for (int n = 0; n < 4; ++n) {
      int key = key0 + n * 16 + cL;
#pragma unroll
      for (int r = 0; r < 4; ++r)
        sx[n][r] = fmaf(sa[n][r], 0.25f, brh[key - (qrow0 + r)]);
    }
    // ---- online softmax (16-lane group reduce)
#pragma unroll
    for (int r = 0; r < 4; ++r) {
      float mx = fmaxf(fmaxf(sx[0][r], sx[1][r]), fmaxf(sx[2][r], sx[3][r]));
      mx = fmaxf(mx, __shfl_xor(mx, 1));
      mx = fmaxf(mx, __shfl_xor(mx, 2));
      mx = fmaxf(mx, __shfl_xor(mx, 4));
      mx = fmaxf(mx, __shfl_xor(mx, 8));
      float mn = fmaxf(m[r], mx);
      float corr = __expf(m[r] - mn);
      float ps = 0.f;
#pragma unroll
      for (int n = 0; n < 4; ++n) {
        float p = __expf(sx[n][r] - mn);
        sx[n][r] = p;
        ps += p;
      }
      ps += __shfl_xor(ps, 1);
      ps += __shfl_xor(ps, 2);
      ps += __shfl_xor(ps, 4);
      ps += __shfl_xor(ps, 8);
      lsum[r] = lsum[r] * corr + ps;
      m[r] = mn;
#pragma unroll
      for (int n = 0; n < 4; ++n) o[n][r] *= corr;
    }
    // ---- P: C-layout regs -> XOR-swizzled LDS -> A-layout fragments
#pragma unroll
    for (int n = 0; n < 4; ++n) {
#pragma unroll
      for (int r = 0; r < 4; ++r) {
        int row = g * 4 + r;
        int byte = row * 128 + ((((n * 16 + cL) * 2)) ^ ((row & 7) << 4));
        *(f16*)(pbase + byte) = (f16)sx[n][r];
      }
    }
    asm volatile("s_waitcnt lgkmcnt(0)" ::: "memory");
    int rb = cL * 128;
    f16x8 pa0 = *(const f16x8*)(pbase + rb + ((g * 16) ^ sw));
    f16x8 pa1 = *(const f16x8*)(pbase + rb + ((64 + g * 16) ^ sw));
    // ---- O += P V from LDS (V^T tile [dk][key])
#pragma unroll
    for (int n = 0; n < 4; ++n) {
      int dk = n * 16 + cL;
      f16x8 v0 = *(const f16x8*)&vb[dk * 64 + ((g ^ (dk & 7)) << 3)];
      f16x8 v1 = *(const f16x8*)&vb[dk * 64 + (((g + 4) ^ (dk & 7)) << 3)];
      o[n] = MFMA16(pa0, v0, o[n]);
      o[n] = MFMA16(pa1, v1, o[n]);
    }
    __syncthreads();
  }
#undef ASTAGE
  // ---- epilogue
#pragma unroll
  for (int r = 0; r < 4; ++r) {
    float inv = 1.0f / lsum[r];
    int q = qrow0 + r;
    size_t rowoff = ((size_t)b * 2048 + q) * 1024 + h * 64;
#pragma unroll
    for (int n = 0; n < 4; ++n)
      Oh[rowoff + n * 16 + cL] = (f16)(o[n][r] * inv);
  }
}

// ---------------------------------------------------------------- launch

extern "C" void kernel_launch(void* const* d_in, const int* in_sizes, int n_in,
                              void* d_out, int out_size, void* d_ws, size_t ws_size,
                              hipStream_t stream) {
  const float* X = (const float*)d_in[0];
  const float* Wq = (const float*)d_in[1];
  const float* Wk = (const float*)d_in[2];
  const float* Wv = (const float*)d_in[3];
  const float* Wo = (const float*)d_in[4];
  const float* relb = (const float*)d_in[5];

  const size_t MB8 = (size_t)8 << 20;
  if (ws_size < 6 * MB8 + (size_t)(16 * 4095) * 4) return;

  char* ws = (char*)d_ws;
  f16* Xh = (f16*)(ws + 0 * MB8);
  f16* Wt = (f16*)(ws + 1 * MB8);
  f16* Qh = (f16*)(ws + 2 * MB8);
  f16* Kh = (f16*)(ws + 3 * MB8);
  f16* Vt = (f16*)(ws + 4 * MB8);
  f16* Oh = (f16*)(ws + 5 * MB8);
  float* brel = (float*)(ws + 6 * MB8);

  cast_x_kernel<<<dim3(4096), dim3(256), 0, stream>>>((const float4*)X, (f16x4*)Xh);
  transpose_w_kernel<<<dim3(32, 32, 4), dim3(32, 8), 0, stream>>>(Wq, Wk, Wv, Wo, Wt);
  bias_kernel<<<dim3(256), dim3(256), 0, stream>>>(relb, brel);
  gemm_qkv_kernel<<<dim3(24, 32), dim3(256), 0, stream>>>(Xh, Wt, Qh, Kh, Vt);
  attn_kernel<<<dim3(32, 32), dim3(256), 0, stream>>>(Qh, Kh, Vt, brel, Oh);
  gemm_out_kernel<<<dim3(8, 32), dim3(256), 0, stream>>>(Oh, Wt + (size_t)3072 * 1024,
                                                         (float*)d_out);
}

// Round 3
// 188.774 us; speedup vs baseline: 2.9105x; 1.0406x over previous
//
#include <hip/hip_runtime.h>
#include <math.h>

// B=2, S=2048, D=1024, H=16, DK=64, NUM_BUCKETS=32, MAX_DIST=128, SM_SCALE=0.25
// Softmax runs in log2 domain: Wq pre-scaled by 0.25*log2(e), bias table pre-scaled by log2(e).

typedef _Float16 f16;
typedef _Float16 f16x4 __attribute__((ext_vector_type(4)));
typedef _Float16 f16x8 __attribute__((ext_vector_type(8)));
typedef float f32x4 __attribute__((ext_vector_type(4)));

#define MFMA16(a, b, c) __builtin_amdgcn_mfma_f32_16x16x32_f16((a), (b), (c), 0, 0, 0)

#if __has_builtin(__builtin_amdgcn_exp2f)
#define EXP2(x) __builtin_amdgcn_exp2f(x)
#else
static __device__ __forceinline__ float EXP2(float x) {
  float r;
  asm("v_exp_f32 %0, %1" : "=v"(r) : "v"(x));
  return r;
}
#endif

// async global->LDS, 16B per lane; lds base must be wave-uniform (HW adds lane*16)
__device__ __forceinline__ void gload16(const f16* g, f16* l) {
  __builtin_amdgcn_global_load_lds(
      (const __attribute__((address_space(1))) void*)g,
      (__attribute__((address_space(3))) void*)l, 16, 0, 0);
}

// ---------------------------------------------------------------- prep kernels

__global__ __launch_bounds__(256) void cast_x_kernel(const float4* __restrict__ x,
                                                     f16x4* __restrict__ xh) {
  int i = blockIdx.x * 256 + threadIdx.x;
  float4 v = x[i];
  f16x4 o;
  o[0] = (f16)v.x; o[1] = (f16)v.y; o[2] = (f16)v.z; o[3] = (f16)v.w;
  xh[i] = o;
}

// W[k][n] (1024x1024 fp32) -> Wt[z*1024 + n][k] f16; Wq scaled by 0.25*log2e
__global__ void transpose_w_kernel(const float* __restrict__ w0, const float* __restrict__ w1,
                                   const float* __restrict__ w2, const float* __restrict__ w3,
                                   f16* __restrict__ wt) {
  int z = blockIdx.z;
  const float* w = (z == 0) ? w0 : (z == 1) ? w1 : (z == 2) ? w2 : w3;
  float sc = (z == 0) ? 0.36067376022224085f : 1.0f;  // 0.25 * log2(e)
  __shared__ float tile[32][33];
  int tx = threadIdx.x, ty = threadIdx.y;
  int kt = blockIdx.x * 32, nt = blockIdx.y * 32;
#pragma unroll
  for (int i = 0; i < 4; ++i)
    tile[ty + i * 8][tx] = w[(size_t)(kt + ty + i * 8) * 1024 + nt + tx];
  __syncthreads();
#pragma unroll
  for (int i = 0; i < 4; ++i)
    wt[((size_t)z * 1024 + nt + ty + i * 8) * 1024 + kt + tx] = (f16)(tile[tx][ty + i * 8] * sc);
}

// T5 bias table, log2e-scaled, layout [h][4096] with index rp+2048 (rp in [-2047,2047])
__global__ __launch_bounds__(256) void bias_kernel(const float* __restrict__ rel_bias,
                                                   float* __restrict__ bias_rel) {
  int idx = blockIdx.x * 256 + threadIdx.x;  // 65536 total
  int h = idx >> 12;
  int r = idx & 4095;
  int rp = r - 2048;
  if (rp < -2047) rp = -2047;
  int bucket = (rp > 0) ? 16 : 0;
  int rpa = (rp < 0) ? -rp : rp;
  if (rpa < 8) {
    bucket += rpa;
  } else {
    int large = 8 + (int)(logf((float)rpa / 8.0f) / logf(16.0f) * 8.0f);
    bucket += (large < 15) ? large : 15;
  }
  bias_rel[idx] = rel_bias[bucket * 16 + h] * 1.4426950408889634f;
}

// ---------------------------------------------------------------- GEMM 128x128, BK=32
__device__ __forceinline__ void gemm128_core(const f16* __restrict__ A, const f16* __restrict__ Bt,
                                             int mrow, int ncol0, f16* sm /*[2][8192]*/,
                                             f32x4 acc[4][4]) {
  const int t = threadIdx.x;
  const int lane = t & 63, w = t >> 6;
  const int cL = lane & 15, g = lane >> 4;
  const int wr = w >> 1, wc = w & 1;

  const int c0 = w * 128 + lane;
  const int c1 = c0 + 64;
  const int rA0 = c0 >> 2, kA0 = ((c0 & 3) ^ (rA0 & 3)) << 3;
  const int rA1 = c1 >> 2, kA1 = ((c1 & 3) ^ (rA1 & 3)) << 3;
  const f16* gA0 = A + (size_t)(mrow + rA0) * 1024 + kA0;
  const f16* gA1 = A + (size_t)(mrow + rA1) * 1024 + kA1;
  const f16* gB0 = Bt + (size_t)(ncol0 + rA0) * 1024 + kA0;
  const f16* gB1 = Bt + (size_t)(ncol0 + rA1) * 1024 + kA1;
  const int lds0 = (w * 2) * 512, lds1 = (w * 2 + 1) * 512;

#define GSTAGE(buf, k0)                            \
  do {                                             \
    f16* s_ = sm + (buf) * 8192;                   \
    gload16(gA0 + (k0), s_ + lds0);                \
    gload16(gA1 + (k0), s_ + lds1);                \
    gload16(gB0 + (k0), s_ + 4096 + lds0);         \
    gload16(gB1 + (k0), s_ + 4096 + lds1);         \
  } while (0)

  GSTAGE(0, 0);
  __syncthreads();
#pragma unroll 2
  for (int ks = 0; ks < 32; ++ks) {
    const int cur = ks & 1;
    if (ks < 31) GSTAGE(cur ^ 1, (ks + 1) * 32);
    const f16* bA = sm + cur * 8192;
    const f16* bB = bA + 4096;
    f16x8 af[4], bf[4];
#pragma unroll
    for (int m = 0; m < 4; ++m) {
      int r = wr * 64 + m * 16 + cL;
      af[m] = *(const f16x8*)&bA[r * 32 + ((g ^ (r & 3)) << 3)];
    }
#pragma unroll
    for (int n = 0; n < 4; ++n) {
      int r = wc * 64 + n * 16 + cL;
      bf[n] = *(const f16x8*)&bB[r * 32 + ((g ^ (r & 3)) << 3)];
    }
#pragma unroll
    for (int m = 0; m < 4; ++m)
#pragma unroll
      for (int n = 0; n < 4; ++n) acc[m][n] = MFMA16(af[m], bf[n], acc[m][n]);
    __syncthreads();
  }
#undef GSTAGE
}

// QKV projection -> Q,K [b][h][s][dk], V^T [b][h][dk][s]
__global__ __launch_bounds__(256) void gemm_qkv_kernel(const f16* __restrict__ Xh,
                                                       const f16* __restrict__ Wt,
                                                       f16* __restrict__ Qh,
                                                       f16* __restrict__ Kh,
                                                       f16* __restrict__ Vt) {
  __shared__ __align__(16) f16 sm[2][8192];
  int mrow = blockIdx.y * 128, ncol0 = blockIdx.x * 128;
  f32x4 acc[4][4] = {};
  gemm128_core(Xh, Wt, mrow, ncol0, &sm[0][0], acc);
  int lane = threadIdx.x & 63, w = threadIdx.x >> 6;
  int cL = lane & 15, g = lane >> 4;
  int wr = w >> 1, wc = w & 1;
  int which = (ncol0 + wc * 64) >> 10;
#pragma unroll
  for (int m = 0; m < 4; ++m) {
#pragma unroll
    for (int n = 0; n < 4; ++n) {
#pragma unroll
      for (int r = 0; r < 4; ++r) {
        int tt = mrow + wr * 64 + m * 16 + g * 4 + r;
        int b = tt >> 11, s = tt & 2047;
        int col = (ncol0 + wc * 64 + n * 16 + cL) & 1023;
        int hh = col >> 6, dk = col & 63;
        f16 val = (f16)acc[m][n][r];
        if (which == 0)
          Qh[(((size_t)b * 16 + hh) * 2048 + s) * 64 + dk] = val;
        else if (which == 1)
          Kh[(((size_t)b * 16 + hh) * 2048 + s) * 64 + dk] = val;
        else
          Vt[(((size_t)b * 16 + hh) * 64 + dk) * 2048 + s] = val;
      }
    }
  }
}

// Output projection -> fp32 d_out
__global__ __launch_bounds__(256) void gemm_out_kernel(const f16* __restrict__ Oh,
                                                       const f16* __restrict__ WoT,
                                                       float* __restrict__ out) {
  __shared__ __align__(16) f16 sm[2][8192];
  int mrow = blockIdx.y * 128, ncol0 = blockIdx.x * 128;
  f32x4 acc[4][4] = {};
  gemm128_core(Oh, WoT, mrow, ncol0, &sm[0][0], acc);
  int lane = threadIdx.x & 63, w = threadIdx.x >> 6;
  int cL = lane & 15, g = lane >> 4;
  int wr = w >> 1, wc = w & 1;
#pragma unroll
  for (int m = 0; m < 4; ++m)
#pragma unroll
    for (int n = 0; n < 4; ++n)
#pragma unroll
      for (int r = 0; r < 4; ++r) {
        int tt = mrow + wr * 64 + m * 16 + g * 4 + r;
        out[(size_t)tt * 1024 + ncol0 + wc * 64 + n * 16 + cL] = acc[m][n][r];
      }
}

// ---------------------------------------------------------------- attention
// Grid (S/64, B*H), 4 waves/block each owning 16 q-rows. K/V tiles LDS double-buffered.
// Bias slice staged in LDS; QK^T accumulator initialized with bias (C is add-in).
// Softmax in log2 domain with defer-max (THR=8); per-lane partial lsum, reduced at end.
__global__ __launch_bounds__(256) void attn_kernel(const f16* __restrict__ Qh,
                                                   const f16* __restrict__ Kh,
                                                   const f16* __restrict__ Vt,
                                                   const float* __restrict__ bias_rel,
                                                   f16* __restrict__ Oh) {
  __shared__ __align__(16) f16 sKV[2][8192];  // [buf][ K 4096 | V 4096 ]
  __shared__ __align__(16) char sP[4][2048];  // per-wave P roundtrip
  __shared__ __align__(16) float sB[2176];    // bias slice
  int bh = blockIdx.y;
  int h = bh & 15, b = bh >> 4;
  int qt = blockIdx.x * 64;
  int lane = threadIdx.x & 63, wave = threadIdx.x >> 6;
  int cL = lane & 15, g = lane >> 4;
  const size_t bhS = (size_t)bh * 2048;

  // Q A-fragments (Q already scaled by 0.25*log2e)
  const f16* qp = Qh + (bhS + qt + wave * 16 + cL) * 64 + 8 * g;
  f16x8 qa0 = *(const f16x8*)qp;
  f16x8 qa1 = *(const f16x8*)(qp + 32);

  // stage bias slice: sB[j] = bias_rel[h*4096 + 1984 - qt + j]; lookup j = k - (q-qt) + 64 + qt-? see bp
  {
    const float4* gB = (const float4*)(bias_rel + (size_t)h * 4096 + 1984 - qt);
    for (int i = threadIdx.x; i < 544; i += 256) ((float4*)sB)[i] = gB[i];
  }

  // staging descriptors (chunk = 16B = 8 f16)
  const int c0 = wave * 128 + lane;
  const int c1 = c0 + 64;
  const int r0 = c0 >> 3, cc0 = ((c0 & 7) ^ (r0 & 7)) << 3;
  const int r1 = c1 >> 3, cc1 = ((c1 & 7) ^ (r1 & 7)) << 3;
  const f16* gK0 = Kh + (bhS + r0) * 64 + cc0;
  const f16* gK1 = Kh + (bhS + r1) * 64 + cc1;
  const f16* gV0 = Vt + ((size_t)bh * 64 + r0) * 2048 + cc0;
  const f16* gV1 = Vt + ((size_t)bh * 64 + r1) * 2048 + cc1;
  const int lds0 = (wave * 2) * 512, lds1 = (wave * 2 + 1) * 512;

#define ASTAGE(buf, key0)                          \
  do {                                             \
    f16* s_ = &sKV[buf][0];                        \
    gload16(gK0 + (size_t)(key0) * 64, s_ + lds0); \
    gload16(gK1 + (size_t)(key0) * 64, s_ + lds1); \
    gload16(gV0 + (key0), s_ + 4096 + lds0);       \
    gload16(gV1 + (key0), s_ + 4096 + lds1);       \
  } while (0)

  // bias lane base: bias(q,k) = sB[k - (q-qt) + 64], q-qt = wave*16+g*4+r
  // bp chosen so all immediate offsets are >= 0: sB[key0 + n*16 + (3-r) + base]
  const float* bp = sB + (cL - wave * 16 - g * 4 + 61);

  f32x4 o[4] = {};
  float m[4] = {-INFINITY, -INFINITY, -INFINITY, -INFINITY};
  float lsum[4] = {0.f, 0.f, 0.f, 0.f};
  char* pbase = sP[wave];
  const int sw = (cL & 7) << 4;

  ASTAGE(0, 0);
  __syncthreads();
  for (int kt = 0; kt < 32; ++kt) {
    const int cur = kt & 1;
    if (kt < 31) ASTAGE(cur ^ 1, (kt + 1) * 64);
    const int key0 = kt * 64;
    const f16* kb = &sKV[cur][0];
    const f16* vb = kb + 4096;
    // ---- S2 = bias2 + Q' K^T  (accumulator initialized with bias)
    f32x4 sa[4];
#pragma unroll
    for (int n = 0; n < 4; ++n)
#pragma unroll
      for (int r = 0; r < 4; ++r) sa[n][r] = bp[key0 + n * 16 + 3 - r];
#pragma unroll
    for (int n = 0; n < 4; ++n) {
      int key = n * 16 + cL;
      f16x8 b0 = *(const f16x8*)&kb[key * 64 + ((g ^ (key & 7)) << 3)];
      f16x8 b1 = *(const f16x8*)&kb[key * 64 + (((g + 4) ^ (key & 7)) << 3)];
      sa[n] = MFMA16(qa0, b0, sa[n]);
      sa[n] = MFMA16(qa1, b1, sa[n]);
    }
    // ---- row max (16-lane group reduce)
    float mx[4];
#pragma unroll
    for (int r = 0; r < 4; ++r) {
      float v = fmaxf(fmaxf(sa[0][r], sa[1][r]), fmaxf(sa[2][r], sa[3][r]));
      v = fmaxf(v, __shfl_xor(v, 1));
      v = fmaxf(v, __shfl_xor(v, 2));
      v = fmaxf(v, __shfl_xor(v, 4));
      v = fmaxf(v, __shfl_xor(v, 8));
      mx[r] = v;
    }
    // ---- defer-max: rescale only when a row max grew by > 8 (log2 units)
    bool grow = (mx[0] > m[0] + 8.f) || (mx[1] > m[1] + 8.f) ||
                (mx[2] > m[2] + 8.f) || (mx[3] > m[3] + 8.f);
    if (__any(grow)) {
#pragma unroll
      for (int r = 0; r < 4; ++r) {
        float mn = fmaxf(m[r], mx[r]);
        float corr = EXP2(m[r] - mn);
        lsum[r] *= corr;
        m[r] = mn;
#pragma unroll
        for (int n = 0; n < 4; ++n) o[n][r] *= corr;
      }
    }
    // ---- P = exp2(S2 - m), store to swizzled LDS, accumulate per-lane lsum
#pragma unroll
    for (int n = 0; n < 4; ++n) {
#pragma unroll
      for (int r = 0; r < 4; ++r) {
        float p = EXP2(sa[n][r] - m[r]);
        lsum[r] += p;
        int row = g * 4 + r;
        int byte = row * 128 + (((n * 16 + cL) * 2) ^ ((row & 7) << 4));
        *(f16*)(pbase + byte) = (f16)p;
      }
    }
    asm volatile("s_waitcnt lgkmcnt(0)" ::: "memory");
    int rb = cL * 128;
    f16x8 pa0 = *(const f16x8*)(pbase + rb + ((g * 16) ^ sw));
    f16x8 pa1 = *(const f16x8*)(pbase + rb + ((64 + g * 16) ^ sw));
    // ---- O += P V from LDS (V^T tile [dk][key])
#pragma unroll
    for (int n = 0; n < 4; ++n) {
      int dk = n * 16 + cL;
      f16x8 v0 = *(const f16x8*)&vb[dk * 64 + ((g ^ (dk & 7)) << 3)];
      f16x8 v1 = *(const f16x8*)&vb[dk * 64 + (((g + 4) ^ (dk & 7)) << 3)];
      o[n] = MFMA16(pa0, v0, o[n]);
      o[n] = MFMA16(pa1, v1, o[n]);
    }
    __syncthreads();
  }
#undef ASTAGE
  // ---- epilogue: reduce lsum across the 16-lane group, normalize, store
  const int qrow0 = qt + wave * 16 + g * 4;
#pragma unroll
  for (int r = 0; r < 4; ++r) {
    float s = lsum[r];
    s += __shfl_xor(s, 1);
    s += __shfl_xor(s, 2);
    s += __shfl_xor(s, 4);
    s += __shfl_xor(s, 8);
    float inv = 1.0f / s;
    int q = qrow0 + r;
    size_t rowoff = ((size_t)b * 2048 + q) * 1024 + h * 64;
#pragma unroll
    for (int n = 0; n < 4; ++n)
      Oh[rowoff + n * 16 + cL] = (f16)(o[n][r] * inv);
  }
}

// ---------------------------------------------------------------- launch

extern "C" void kernel_launch(void* const* d_in, const int* in_sizes, int n_in,
                              void* d_out, int out_size, void* d_ws, size_t ws_size,
                              hipStream_t stream) {
  const float* X = (const float*)d_in[0];
  const float* Wq = (const float*)d_in[1];
  const float* Wk = (const float*)d_in[2];
  const float* Wv = (const float*)d_in[3];
  const float* Wo = (const float*)d_in[4];
  const float* relb = (const float*)d_in[5];

  const size_t MB8 = (size_t)8 << 20;
  if (ws_size < 6 * MB8 + (1 << 19)) return;

  char* ws = (char*)d_ws;
  f16* Xh = (f16*)(ws + 0 * MB8);
  f16* Wt = (f16*)(ws + 1 * MB8);
  f16* Qh = (f16*)(ws + 2 * MB8);
  f16* Kh = (f16*)(ws + 3 * MB8);
  f16* Vt = (f16*)(ws + 4 * MB8);
  f16* Oh = (f16*)(ws + 5 * MB8);
  float* brel = (float*)(ws + 6 * MB8);  // [16][4096] log2e-scaled

  cast_x_kernel<<<dim3(4096), dim3(256), 0, stream>>>((const float4*)X, (f16x4*)Xh);
  transpose_w_kernel<<<dim3(32, 32, 4), dim3(32, 8), 0, stream>>>(Wq, Wk, Wv, Wo, Wt);
  bias_kernel<<<dim3(256), dim3(256), 0, stream>>>(relb, brel);
  gemm_qkv_kernel<<<dim3(24, 32), dim3(256), 0, stream>>>(Xh, Wt, Qh, Kh, Vt);
  attn_kernel<<<dim3(32, 32), dim3(256), 0, stream>>>(Qh, Kh, Vt, brel, Oh);
  gemm_out_kernel<<<dim3(8, 32), dim3(256), 0, stream>>>(Oh, Wt + (size_t)3072 * 1024,
                                                         (float*)d_out);
}